// Round 2
// 265.773 us; speedup vs baseline: 1.0008x; 1.0008x over previous
//
#include <hip/hip_runtime.h>
#include <math.h>

#define NFEAT 1024
#define NROWS 32768
#define EPS 1e-5f

#define NB1 1024                       // stage-1 blocks
#define RPB1 (NROWS / NB1)             // 32 rows per stage-1 block
#define FG (NFEAT / 4)                 // 256 float4 col-groups per row
#define NB2 FG                         // stage-2: one block per col-group
#define NB3 2048                       // norm blocks
#define RPB3 (NROWS / NB3)             // 16 rows per norm block

// native vector type: accepted by __builtin_nontemporal_store (HIP float4 is not)
typedef float f32x4 __attribute__((ext_vector_type(4)));

// ws layout (floats):
//   [0      .. 1023 ]  mean        (written by reduce2, read by norm)
//   [1024   .. 2047 ]  inv_std     (written by reduce2, read by norm)
//   [2048   .. ]       partial_s: NB1*FG float4s, then partial_q: NB1*FG float4s
// No part of ws is read before being written this launch -> no memset needed.

__global__ __launch_bounds__(256) void reduce1_kernel(
    const float* __restrict__ x, float4* __restrict__ ps, float4* __restrict__ pq)
{
    const int t = threadIdx.x;                 // col-group 0..255
    const size_t base = (size_t)(blockIdx.x * RPB1) * FG + t;
    const float4* xv = (const float4*)x;

    float4 s = make_float4(0.f, 0.f, 0.f, 0.f);
    float4 q = make_float4(0.f, 0.f, 0.f, 0.f);

    #pragma unroll
    for (int r = 0; r < RPB1; r += 4) {
        // 4 independent loads in flight per wave
        float4 v0 = xv[base + (size_t)(r + 0) * FG];
        float4 v1 = xv[base + (size_t)(r + 1) * FG];
        float4 v2 = xv[base + (size_t)(r + 2) * FG];
        float4 v3 = xv[base + (size_t)(r + 3) * FG];
        s.x += v0.x + v1.x + v2.x + v3.x;
        s.y += v0.y + v1.y + v2.y + v3.y;
        s.z += v0.z + v1.z + v2.z + v3.z;
        s.w += v0.w + v1.w + v2.w + v3.w;
        q.x = fmaf(v0.x, v0.x, fmaf(v1.x, v1.x, fmaf(v2.x, v2.x, fmaf(v3.x, v3.x, q.x))));
        q.y = fmaf(v0.y, v0.y, fmaf(v1.y, v1.y, fmaf(v2.y, v2.y, fmaf(v3.y, v3.y, q.y))));
        q.z = fmaf(v0.z, v0.z, fmaf(v1.z, v1.z, fmaf(v2.z, v2.z, fmaf(v3.z, v3.z, q.z))));
        q.w = fmaf(v0.w, v0.w, fmaf(v1.w, v1.w, fmaf(v2.w, v2.w, fmaf(v3.w, v3.w, q.w))));
    }
    ps[(size_t)blockIdx.x * FG + t] = s;       // no atomics
    pq[(size_t)blockIdx.x * FG + t] = q;
}

// 256 blocks (one col-group each) x 256 threads: full-grid, deterministic,
// no atomics, and finalizes mean / 1/(std+eps) so norm does no stats math
// and no memset is needed.
__global__ __launch_bounds__(256) void reduce2_kernel(
    const float4* __restrict__ ps, const float4* __restrict__ pq,
    float4* __restrict__ mean, float4* __restrict__ inv)
{
    const int t = threadIdx.x;
    const int cg = blockIdx.x;                 // col-group 0..255

    float4 s = make_float4(0.f, 0.f, 0.f, 0.f);
    float4 q = make_float4(0.f, 0.f, 0.f, 0.f);
    #pragma unroll
    for (int k = 0; k < NB1 / 256; ++k) {      // 4 partial-rows per thread
        float4 a = ps[(size_t)(t + 256 * k) * FG + cg];
        float4 b = pq[(size_t)(t + 256 * k) * FG + cg];
        s.x += a.x; s.y += a.y; s.z += a.z; s.w += a.w;
        q.x += b.x; q.y += b.y; q.z += b.z; q.w += b.w;
    }

    __shared__ float4 ls[256];
    __shared__ float4 lq[256];
    ls[t] = s; lq[t] = q;
    __syncthreads();
    #pragma unroll
    for (int off = 128; off > 0; off >>= 1) {
        if (t < off) {
            float4 a = ls[t + off];
            ls[t].x += a.x; ls[t].y += a.y; ls[t].z += a.z; ls[t].w += a.w;
            float4 b = lq[t + off];
            lq[t].x += b.x; lq[t].y += b.y; lq[t].z += b.z; lq[t].w += b.w;
        }
        __syncthreads();
    }

    if (t == 0) {
        float4 S = ls[0], Q = lq[0];
        const float n   = (float)NROWS;
        const float rn  = 1.0f / n;
        const float rn1 = 1.0f / (n - 1.0f);
        float4 m, iv;
        m.x = S.x * rn; m.y = S.y * rn; m.z = S.z * rn; m.w = S.w * rn;
        iv.x = 1.0f / (sqrtf((Q.x - S.x * S.x * rn) * rn1) + EPS);
        iv.y = 1.0f / (sqrtf((Q.y - S.y * S.y * rn) * rn1) + EPS);
        iv.z = 1.0f / (sqrtf((Q.z - S.z * S.z * rn) * rn1) + EPS);
        iv.w = 1.0f / (sqrtf((Q.w - S.w * S.w * rn) * rn1) + EPS);
        mean[cg] = m;
        inv[cg]  = iv;
    }
}

__global__ __launch_bounds__(256) void norm_kernel(
    const float* __restrict__ x,
    const float4* __restrict__ mean, const float4* __restrict__ inv,
    float* __restrict__ out)
{
    const int t = threadIdx.x;
    const size_t base = (size_t)(blockIdx.x * RPB3) * FG + t;
    const f32x4* xv = (const f32x4*)x;
    f32x4* ov = (f32x4*)out;

    const float4 m  = mean[t];
    const float4 iv = inv[t];

    #pragma unroll
    for (int r = 0; r < RPB3; r += 4) {
        f32x4 v0 = xv[base + (size_t)(r + 0) * FG];
        f32x4 v1 = xv[base + (size_t)(r + 1) * FG];
        f32x4 v2 = xv[base + (size_t)(r + 2) * FG];
        f32x4 v3 = xv[base + (size_t)(r + 3) * FG];
        f32x4 o0, o1, o2, o3;
        o0.x = (v0.x - m.x) * iv.x; o0.y = (v0.y - m.y) * iv.y;
        o0.z = (v0.z - m.z) * iv.z; o0.w = (v0.w - m.w) * iv.w;
        o1.x = (v1.x - m.x) * iv.x; o1.y = (v1.y - m.y) * iv.y;
        o1.z = (v1.z - m.z) * iv.z; o1.w = (v1.w - m.w) * iv.w;
        o2.x = (v2.x - m.x) * iv.x; o2.y = (v2.y - m.y) * iv.y;
        o2.z = (v2.z - m.z) * iv.z; o2.w = (v2.w - m.w) * iv.w;
        o3.x = (v3.x - m.x) * iv.x; o3.y = (v3.y - m.y) * iv.y;
        o3.z = (v3.z - m.z) * iv.z; o3.w = (v3.w - m.w) * iv.w;
        // nontemporal: out is never re-read; keep x resident in L3 instead
        __builtin_nontemporal_store(o0, &ov[base + (size_t)(r + 0) * FG]);
        __builtin_nontemporal_store(o1, &ov[base + (size_t)(r + 1) * FG]);
        __builtin_nontemporal_store(o2, &ov[base + (size_t)(r + 2) * FG]);
        __builtin_nontemporal_store(o3, &ov[base + (size_t)(r + 3) * FG]);
    }
}

extern "C" void kernel_launch(void* const* d_in, const int* in_sizes, int n_in,
                              void* d_out, int out_size, void* d_ws, size_t ws_size,
                              hipStream_t stream) {
    const float* x = (const float*)d_in[0];
    float* out = (float*)d_out;

    float* mean = (float*)d_ws;                      // [1024]
    float* inv  = mean + NFEAT;                      // [1024]
    float4* ps = (float4*)(inv + NFEAT);             // NB1*FG float4s (4 MB)
    float4* pq = ps + (size_t)NB1 * FG;              // NB1*FG float4s (4 MB)

    reduce1_kernel<<<NB1, 256, 0, stream>>>(x, ps, pq);
    reduce2_kernel<<<NB2, 256, 0, stream>>>(ps, pq, (float4*)mean, (float4*)inv);
    norm_kernel<<<NB3, 256, 0, stream>>>(x, (float4*)mean, (float4*)inv, out);
}